// Round 15
// baseline (57.198 us; speedup 1.0000x reference)
//
#include <hip/hip_runtime.h>
#include <hip/hip_bf16.h>
#include <stdint.h>

#define HEIGHT 32
#define WIDTH  8192
#define KDIM   256
#define NDIM   512
#define NSLICES 65536                 // B * S = 64 * 1024
#define NMTILES 2048                  // 32 slices per mtile

typedef float f32x4  __attribute__((ext_vector_type(4)));
typedef float f32x16 __attribute__((ext_vector_type(16)));
typedef short bf16x8 __attribute__((ext_vector_type(8)));

#define GLOAD_LDS16(g, l)                                                       \
  __builtin_amdgcn_global_load_lds(                                             \
      (const __attribute__((address_space(1))) void*)(g),                       \
      (__attribute__((address_space(3))) void*)(l), 16, 0, 0)

__device__ __forceinline__ ushort f2bf(float x) {
  union { float f; uint32_t u; } un; un.f = x;
  uint32_t u = un.u;
  u += 0x7FFFu + ((u >> 16) & 1u);   // round-to-nearest-even
  return (ushort)(u >> 16);
}

__device__ __forceinline__ void load_row8(float* r, const float* p) {
  f32x4 lo = *reinterpret_cast<const f32x4*>(p);
  f32x4 hi = *reinterpret_cast<const f32x4*>(p + 4);
#pragma unroll
  for (int w = 0; w < 4; ++w) { r[w] = lo[w]; r[4 + w] = hi[w]; }
}

// ---- wt2: B-fragment-tiled layout (proven R7-R13) ----
// wt2[((nb*16 + k0)*64 + lane)*8 + e] = bf16(lin_w[k][n]),
//   n = nb*32 + (lane&31), k = k0*16 + (lane>>5)*8 + e.
__global__ __launch_bounds__(256) void prep_wt2_kernel(const float* __restrict__ lin_w,
                                                       ushort* __restrict__ wt2) {
  const int idx = blockIdx.x * 256 + threadIdx.x;   // 0..16383
  const int ln  = idx & 63;
  const int k0  = (idx >> 6) & 15;
  const int nb  = idx >> 10;
  const int n   = nb * 32 + (ln & 31);
  const int kb  = k0 * 16 + (ln >> 5) * 8;
  bf16x8 p;
#pragma unroll
  for (int e = 0; e < 8; ++e) p[e] = (short)f2bf(lin_w[(size_t)(kb + e) * NDIM + n]);
  *reinterpret_cast<bf16x8*>(wt2 + (size_t)idx * 8) = p;
}

// ---------------- fused: conv -> LDS A-frags; B via fenced async global_load_lds ----------------
// Block = 1 mtile (32 slices), 256 threads. K-loop per wave:
//   (1) s_waitcnt lgkmcnt(0) + sched_barrier  -- prev ds_reads done, safe to overwrite ring
//   (2) issue next k0's 4 B-frags via global_load_lds (1 KB each, wave-uniform LDS base)
//   (3) s_waitcnt vmcnt(4) + sched_barrier    -- current k0's frags have landed
//   (4) ds_read A + 4 B frags, 4 MFMA
// No barriers in the loop: each wave consumes only fragments it issued itself.
__global__ __launch_bounds__(256) void fused_kernel(
    const float* __restrict__ images, const float* __restrict__ conv_w,
    const float* __restrict__ conv_b, const ushort* __restrict__ wt2,
    const float* __restrict__ lin_b, float* __restrict__ out) {
  __shared__ ushort A[16 * 64 * 8];   // 16 KB, A-fragment order
  __shared__ ushort Bb[2][16][512];   // 32 KB: [ring][wv*4+nf][frag]

  const int tid = threadIdx.x;
  const int blk = blockIdx.x;         // mtile

  float cw[9];
#pragma unroll
  for (int i = 0; i < 9; ++i) cw[i] = conv_w[i];
  const float cb = conv_b[0];

  // ---------- phase 1: conv 32 slices x 32 rows -> A-frags in LDS ----------
  {
    const int sl = tid & 31;          // slice within mtile
    const int q  = tid >> 5;          // 0..7: rows q*4 .. q*4+3
    const int s  = blk * 32 + sl;     // global slice
    const int b  = s >> 10;           // batch (1024 slices per batch)
    const int slb = s & 1023;
    const float* base = images + (size_t)b * (HEIGHT * WIDTH) + (size_t)slb * 8;
    const int h0 = q * 4;

    float pr[8], cu[8], nx[8];
    if (h0 > 0) load_row8(pr, base + (size_t)(h0 - 1) * WIDTH);
    else {
#pragma unroll
      for (int w = 0; w < 8; ++w) pr[w] = 0.f;
    }
    load_row8(cu, base + (size_t)h0 * WIDTH);

#pragma unroll
    for (int i = 0; i < 4; ++i) {
      const int h = h0 + i;
      if (h + 1 < HEIGHT) load_row8(nx, base + (size_t)(h + 1) * WIDTH);
      else {
#pragma unroll
        for (int w = 0; w < 8; ++w) nx[w] = 0.f;
      }
      float y[8];
#pragma unroll
      for (int w = 0; w < 8; ++w) y[w] = cb;
#pragma unroll
      for (int dw = 0; dw < 3; ++dw) {
        const float c0 = cw[dw], c1 = cw[3 + dw], c2 = cw[6 + dw];
#pragma unroll
        for (int w = 0; w < 8; ++w) {
          const int iw = w + dw - 1;            // per-slice zero padding in w
          if (iw >= 0 && iw < 8) {
            y[w] = fmaf(pr[iw], c0, y[w]);
            y[w] = fmaf(cu[iw], c1, y[w]);
            y[w] = fmaf(nx[iw], c2, y[w]);
          }
        }
      }
      bf16x8 pack;
#pragma unroll
      for (int w = 0; w < 8; ++w) pack[w] = (short)f2bf(fmaxf(y[w], 0.f));
      const int ln = ((h & 1) << 5) | sl;
      const int k0 = h >> 1;
      *reinterpret_cast<bf16x8*>(A + ((size_t)k0 * 64 + ln) * 8) = pack;
#pragma unroll
      for (int w = 0; w < 8; ++w) { pr[w] = cu[w]; cu[w] = nx[w]; }
    }
  }
  __syncthreads();

  // ---------- phase 2: [32 x 256] @ [256 x 512]; fenced async B pipeline ----------
  const int lane = tid & 63;
  const int wv   = tid >> 6;
  const int la   = lane & 31;
  const int lb   = lane >> 5;

  // per-lane global source of frag (nf, k): this lane's 16 B within the 1 KB frag
  const ushort* bsrc = wt2 + (size_t)lane * 8;
#define BFRAG_SRC(nf, k) (bsrc + (((wv * 4 + (nf)) * 16 + (k)) * 512))

  // prologue: issue k0=0's 4 frags into ring 0
#pragma unroll
  for (int nf = 0; nf < 4; ++nf)
    GLOAD_LDS16(BFRAG_SRC(nf, 0), &Bb[0][wv * 4 + nf][0]);

  f32x16 acc[4];
#pragma unroll
  for (int nf = 0; nf < 4; ++nf)
#pragma unroll
    for (int i = 0; i < 16; ++i) acc[nf][i] = 0.f;

  const ushort* abase = A + (size_t)lane * 8;

#pragma unroll
  for (int k0 = 0; k0 < 16; ++k0) {
    const int cur = k0 & 1;
    if (k0 < 15) {
      // (1) previous iteration's ds_reads must be complete before the DMA that
      // overwrites their buffer can be issued (DMA writes are unordered vs lgkm)
      asm volatile("s_waitcnt lgkmcnt(0)" ::: "memory");
      __builtin_amdgcn_sched_barrier(0);
      const int nxt = cur ^ 1;
#pragma unroll
      for (int nf = 0; nf < 4; ++nf)
        GLOAD_LDS16(BFRAG_SRC(nf, k0 + 1), &Bb[nxt][wv * 4 + nf][0]);
      asm volatile("s_waitcnt vmcnt(4)" ::: "memory");
      __builtin_amdgcn_sched_barrier(0);
    } else {
      asm volatile("s_waitcnt vmcnt(0)" ::: "memory");
      __builtin_amdgcn_sched_barrier(0);
    }

    const bf16x8 af = *reinterpret_cast<const bf16x8*>(abase + (size_t)k0 * 512);
    const bf16x8 b0 = *reinterpret_cast<const bf16x8*>(&Bb[cur][wv * 4 + 0][0] + (size_t)lane * 8);
    const bf16x8 b1 = *reinterpret_cast<const bf16x8*>(&Bb[cur][wv * 4 + 1][0] + (size_t)lane * 8);
    const bf16x8 b2 = *reinterpret_cast<const bf16x8*>(&Bb[cur][wv * 4 + 2][0] + (size_t)lane * 8);
    const bf16x8 b3 = *reinterpret_cast<const bf16x8*>(&Bb[cur][wv * 4 + 3][0] + (size_t)lane * 8);
    acc[0] = __builtin_amdgcn_mfma_f32_32x32x16_bf16(af, b0, acc[0], 0, 0, 0);
    acc[1] = __builtin_amdgcn_mfma_f32_32x32x16_bf16(af, b1, acc[1], 0, 0, 0);
    acc[2] = __builtin_amdgcn_mfma_f32_32x32x16_bf16(af, b2, acc[2], 0, 0, 0);
    acc[3] = __builtin_amdgcn_mfma_f32_32x32x16_bf16(af, b3, acc[3], 0, 0, 0);
  }

  // ---------- epilogue: + bias, fp32 stores ----------
  const size_t row0 = (size_t)blk * 32;
#pragma unroll
  for (int nf = 0; nf < 4; ++nf) {
    const int col = wv * 128 + nf * 32 + la;
    const float bias = lin_b[col];
#pragma unroll
    for (int reg = 0; reg < 16; ++reg) {
      const int rr = (reg & 3) + 8 * (reg >> 2) + 4 * lb;
      out[(row0 + rr) * NDIM + col] = acc[nf][reg] + bias;
    }
  }
}

extern "C" void kernel_launch(void* const* d_in, const int* in_sizes, int n_in,
                              void* d_out, int out_size, void* d_ws, size_t ws_size,
                              hipStream_t stream) {
  const float* images = (const float*)d_in[0];
  const float* conv_w = (const float*)d_in[1];
  const float* conv_b = (const float*)d_in[2];
  const float* lin_w  = (const float*)d_in[3];
  const float* lin_b  = (const float*)d_in[4];
  float* out = (float*)d_out;
  ushort* wt2 = (ushort*)d_ws;      // 256 KB

  hipLaunchKernelGGL(prep_wt2_kernel, dim3(64), dim3(256), 0, stream, lin_w, wt2);
  hipLaunchKernelGGL(fused_kernel, dim3(NMTILES), dim3(256), 0, stream,
                     images, conv_w, conv_b, wt2, lin_b, out);
}